// Round 8
// baseline (147.923 us; speedup 1.0000x reference)
//
#include <hip/hip_runtime.h>

// GCN x2, 3 dispatches:
//   k_zero - zero coarse cursors + grid-barrier counters
//   k_part - partition edges into 98 coarse buckets (1024 nodes), LDS-staged
//            contiguous writeout, records packed (r<<10 | c&1023)
//   k_mega - 196 co-resident blocks (one per 512-node half-bucket), manual
//            device-scope grid barriers:
//            P1: histogram own half -> dinv, y = x*dinv
//            P2: counting-sort own records into LDS, conv1 aggregation over
//                LDS runs (register acc, no atomics), fused 4->64->relu->4
//                matmul, write z = t*dinv
//            P3: re-gather z over same LDS runs, write out = b2 + t*dinv^2
//                + dinv * sum z[r]

#define CSHIFT 10
#define CNODES 1024
#define KC_MAX 128
#define CAPC   18432     // coarse bucket capacity (mean 16384, ~+16 sigma)
#define EPB    4096      // edges per partition block
#define CURPAD 16
#define HCAP   9216      // half-bucket capacity (mean 8192, ~+11 sigma)

__global__ void k_zero(int* __restrict__ p, int n) {
    int i = blockIdx.x * blockDim.x + threadIdx.x;
    if (i < n) p[i] = 0;
}

__global__ void __launch_bounds__(512) k_part(
        const int* __restrict__ row, const int* __restrict__ col,
        int e, int Kc, int* __restrict__ cursor, unsigned* __restrict__ ere) {
    __shared__ int h[KC_MAX];
    __shared__ int loff[KC_MAX];
    __shared__ int gbase[KC_MAX];
    __shared__ int lcur[KC_MAX];
    __shared__ unsigned staged[EPB];
    int t = threadIdx.x;
    if (t < KC_MAX) h[t] = 0;
    __syncthreads();
    int lo = blockIdx.x * EPB;
    int cbuf[8], rbuf[8];
#pragma unroll
    for (int k = 0; k < 8; ++k) {
        int i = lo + t + k * 512;
        if (i < e) { cbuf[k] = col[i]; rbuf[k] = row[i]; }
        else { cbuf[k] = -1; rbuf[k] = 0; }
    }
#pragma unroll
    for (int k = 0; k < 8; ++k)
        if (cbuf[k] >= 0) atomicAdd(&h[cbuf[k] >> CSHIFT], 1);
    __syncthreads();
    if (t < KC_MAX) loff[t] = h[t];
    __syncthreads();
    for (int off = 1; off < KC_MAX; off <<= 1) {
        int v = (t < KC_MAX && t >= off) ? loff[t - off] : 0;
        __syncthreads();
        if (t < KC_MAX) loff[t] += v;
        __syncthreads();
    }
    if (t < KC_MAX) {
        int st = loff[t] - h[t];
        loff[t] = st;
        lcur[t] = st;
        if (t < Kc && h[t]) gbase[t] = atomicAdd(&cursor[t * CURPAD], h[t]);
    }
    __syncthreads();
#pragma unroll
    for (int k = 0; k < 8; ++k) {
        int c = cbuf[k];
        if (c < 0) continue;
        int pos = atomicAdd(&lcur[c >> CSHIFT], 1);
        staged[pos] = ((unsigned)rbuf[k] << CSHIFT) | (unsigned)(c & (CNODES - 1));
    }
    __syncthreads();
    int wid = t >> 6, lane = t & 63;
    for (int k = wid; k < Kc; k += 8) {
        int len = h[k];
        if (!len) continue;
        int gb = gbase[k], lb = loff[k];
        size_t dst = (size_t)k * CAPC + gb;
        for (int j = lane; j < len; j += 64)
            if (gb + j < CAPC) ere[dst + j] = staged[lb + j];
    }
}

__device__ __forceinline__ void grid_barrier(int* bar, int nb, int t) {
    __syncthreads();
    if (t == 0) {
        __threadfence();
        atomicAdd(bar, 1);
        while (atomicAdd(bar, 0) < nb) { }
        __threadfence();
    }
    __syncthreads();
}

__global__ void __launch_bounds__(1024) k_mega(
        const int* __restrict__ cursor, const unsigned* __restrict__ ere,
        const float4* __restrict__ x,
        const float* __restrict__ W1, const float* __restrict__ b1,
        const float* __restrict__ W2, const float* __restrict__ b2,
        float4* __restrict__ y, float4* __restrict__ z,
        float4* __restrict__ out, int n, int nb, int* __restrict__ bar) {
    __shared__ int hist[512];
    __shared__ int scn[512];
    __shared__ int cur[512];
    __shared__ float4 sums[512];
    __shared__ unsigned sorted[HCAP];

    int bh = blockIdx.x;
    int b = bh >> 1, h = bh & 1;
    int t = threadIdx.x;
    int nlo = (b << CSHIFT) + (h << 9);
    int node = nlo + t;                 // valid for t < 512

    // ---- P1: histogram own half ----
    if (t < 512) hist[t] = 0;
    __syncthreads();
    size_t c0 = (size_t)b * CAPC;
    int m = min(cursor[b * CURPAD], CAPC);
    int n4 = m >> 2;
    const uint4* e4 = (const uint4*)(ere + c0);
    for (int g = t; g < n4; g += 1024) {
        uint4 w = e4[g];
        int l0 = w.x & (CNODES - 1); if ((l0 >> 9) == h) atomicAdd(&hist[l0 & 511], 1);
        int l1 = w.y & (CNODES - 1); if ((l1 >> 9) == h) atomicAdd(&hist[l1 & 511], 1);
        int l2 = w.z & (CNODES - 1); if ((l2 >> 9) == h) atomicAdd(&hist[l2 & 511], 1);
        int l3 = w.w & (CNODES - 1); if ((l3 >> 9) == h) atomicAdd(&hist[l3 & 511], 1);
    }
    for (int i = (n4 << 2) + t; i < m; i += 1024) {
        int l = ere[c0 + i] & (CNODES - 1);
        if ((l >> 9) == h) atomicAdd(&hist[l & 511], 1);
    }
    __syncthreads();
    int hv = (t < 512) ? hist[t] : 0;
    if (t < 512) scn[t] = hv;
    __syncthreads();
    for (int off = 1; off < 512; off <<= 1) {
        int v = (t < 512 && t >= off) ? scn[t - off] : 0;
        __syncthreads();
        if (t < 512) scn[t] += v;
        __syncthreads();
    }
    float di = 0.f;
    float4 xv = make_float4(0.f, 0.f, 0.f, 0.f);
    if (t < 512) {
        int st = scn[t] - hv;
        scn[t] = st;
        cur[t] = st;
        if (node < n) {
            di = rsqrtf((float)hv + 1.0f);
            xv = x[node];
            y[node] = make_float4(xv.x * di, xv.y * di, xv.z * di, xv.w * di);
        }
    }
    grid_barrier(bar + 0, nb, t);

    // ---- P2: sort own records into LDS, conv1 agg, matmul, write z ----
    for (int g = t; g < n4; g += 1024) {
        uint4 w = e4[g];
        int l0 = w.x & (CNODES - 1);
        if ((l0 >> 9) == h) { int p = atomicAdd(&cur[l0 & 511], 1); if (p < HCAP) sorted[p] = w.x >> CSHIFT; }
        int l1 = w.y & (CNODES - 1);
        if ((l1 >> 9) == h) { int p = atomicAdd(&cur[l1 & 511], 1); if (p < HCAP) sorted[p] = w.y >> CSHIFT; }
        int l2 = w.z & (CNODES - 1);
        if ((l2 >> 9) == h) { int p = atomicAdd(&cur[l2 & 511], 1); if (p < HCAP) sorted[p] = w.z >> CSHIFT; }
        int l3 = w.w & (CNODES - 1);
        if ((l3 >> 9) == h) { int p = atomicAdd(&cur[l3 & 511], 1); if (p < HCAP) sorted[p] = w.w >> CSHIFT; }
    }
    for (int i = (n4 << 2) + t; i < m; i += 1024) {
        unsigned w = ere[c0 + i];
        int l = w & (CNODES - 1);
        if ((l >> 9) == h) { int p = atomicAdd(&cur[l & 511], 1); if (p < HCAP) sorted[p] = w >> CSHIFT; }
    }
    __syncthreads();
    int tt = t >> 1, q = t & 1;
    int s = scn[tt];
    int ep = min(s + hist[tt], HCAP);
    {
        float vx = 0.f, vy = 0.f, vz = 0.f, vw = 0.f;
        int i = s + q;
        while (i + 6 < ep) {
            unsigned r0 = sorted[i], r1 = sorted[i + 2], r2 = sorted[i + 4], r3 = sorted[i + 6];
            float4 a0 = y[r0], a1 = y[r1], a2 = y[r2], a3 = y[r3];
            vx += a0.x + a1.x + a2.x + a3.x;
            vy += a0.y + a1.y + a2.y + a3.y;
            vz += a0.z + a1.z + a2.z + a3.z;
            vw += a0.w + a1.w + a2.w + a3.w;
            i += 8;
        }
        for (; i < ep; i += 2) {
            float4 a = y[sorted[i]];
            vx += a.x; vy += a.y; vz += a.z; vw += a.w;
        }
        vx += __shfl_xor(vx, 1);
        vy += __shfl_xor(vy, 1);
        vz += __shfl_xor(vz, 1);
        vw += __shfl_xor(vw, 1);
        if (q == 0) sums[tt] = make_float4(vx, vy, vz, vw);
    }
    __syncthreads();
    float t0 = 0.f, t1 = 0.f, t2 = 0.f, t3 = 0.f;
    float sl = di * di;
    if (t < 512 && node < n) {
        float4 sv = sums[t];
        float a0 = di * sv.x + xv.x * sl;
        float a1 = di * sv.y + xv.y * sl;
        float a2 = di * sv.z + xv.z * sl;
        float a3 = di * sv.w + xv.w * sl;
#pragma unroll 8
        for (int j = 0; j < 64; ++j) {
            float hh = b1[j] + a0 * W1[j] + a1 * W1[64 + j] + a2 * W1[128 + j] + a3 * W1[192 + j];
            hh = fmaxf(hh, 0.f);
            t0 += hh * W2[j * 4 + 0];
            t1 += hh * W2[j * 4 + 1];
            t2 += hh * W2[j * 4 + 2];
            t3 += hh * W2[j * 4 + 3];
        }
        z[node] = make_float4(t0 * di, t1 * di, t2 * di, t3 * di);
    }
    grid_barrier(bar + 1, nb, t);

    // ---- P3: re-gather z over same LDS runs, write out ----
    {
        float vx = 0.f, vy = 0.f, vz = 0.f, vw = 0.f;
        int i = s + q;
        while (i + 6 < ep) {
            unsigned r0 = sorted[i], r1 = sorted[i + 2], r2 = sorted[i + 4], r3 = sorted[i + 6];
            float4 a0 = z[r0], a1 = z[r1], a2 = z[r2], a3 = z[r3];
            vx += a0.x + a1.x + a2.x + a3.x;
            vy += a0.y + a1.y + a2.y + a3.y;
            vz += a0.z + a1.z + a2.z + a3.z;
            vw += a0.w + a1.w + a2.w + a3.w;
            i += 8;
        }
        for (; i < ep; i += 2) {
            float4 a = z[sorted[i]];
            vx += a.x; vy += a.y; vz += a.z; vw += a.w;
        }
        vx += __shfl_xor(vx, 1);
        vy += __shfl_xor(vy, 1);
        vz += __shfl_xor(vz, 1);
        vw += __shfl_xor(vw, 1);
        if (q == 0) sums[tt] = make_float4(vx, vy, vz, vw);
    }
    __syncthreads();
    if (t < 512 && node < n) {
        float4 sv = sums[t];
        out[node] = make_float4(b2[0] + t0 * sl + di * sv.x,
                                b2[1] + t1 * sl + di * sv.y,
                                b2[2] + t2 * sl + di * sv.z,
                                b2[3] + t3 * sl + di * sv.w);
    }
}

extern "C" void kernel_launch(void* const* d_in, const int* in_sizes, int n_in,
                              void* d_out, int out_size, void* d_ws, size_t ws_size,
                              hipStream_t stream) {
    const float* x  = (const float*)d_in[0];
    const int* edge = (const int*)d_in[1];
    const float* W1 = (const float*)d_in[2];
    const float* b1 = (const float*)d_in[3];
    const float* W2 = (const float*)d_in[4];
    const float* b2 = (const float*)d_in[5];
    float* out = (float*)d_out;

    const int n = in_sizes[0] / 4;   // N nodes (S=4)
    const int e = in_sizes[1] / 2;   // E edges
    const int* row = edge;
    const int* col = edge + e;
    const int Kc = (n + CNODES - 1) >> CSHIFT;   // 98 coarse buckets
    const int nb = 2 * Kc;                       // 196 mega blocks

    char* ws = (char*)d_ws;
    float* y    = (float*)ws;  ws += (size_t)4 * n * 4;
    float* zmid = (float*)ws;  ws += (size_t)4 * n * 4;
    unsigned* ere = (unsigned*)ws;  ws += (size_t)Kc * CAPC * 4;
    int* cursor = (int*)ws;    ws += (size_t)Kc * CURPAD * 4;
    int* bar    = (int*)ws;    ws += 8 * 4;

    const int B = 256;
    const int gp = (e + EPB - 1) / EPB;          // 391
    const int nz = Kc * CURPAD + 8;              // cursors + barrier counters

    k_zero<<<(nz + B - 1) / B, B, 0, stream>>>(cursor, nz);
    k_part<<<gp, 512, 0, stream>>>(row, col, e, Kc, cursor, ere);
    k_mega<<<nb, 1024, 0, stream>>>(cursor, ere, (const float4*)x,
                                    W1, b1, W2, b2,
                                    (float4*)y, (float4*)zmid,
                                    (float4*)out, n, nb, bar);
}

// Round 10
// 126.924 us; speedup vs baseline: 1.1654x; 1.1654x over previous
//
#include <hip/hip_runtime.h>

// GCN x2. Pipeline (5 dispatches):
//   k_zero  - zero coarse cursors
//   k_part  - partition edges into 98 coarse buckets (1024 nodes each);
//             per-WAVE histograms + placement cursors (4-way LDS-atomic
//             contention vs 32-way), LDS-staged contiguous writeout.
//             Records packed (r<<10 | c&1023).
//   k_sortH - two blocks per bucket; records held in VGPRs (SINGLE global
//             pass, rb[5] covers CAPC): full 1024-bin hist, scan, place own
//             512-node half into LDS sorted order, write back; rstart[],
//             dinv, y = x*dinv.
//   k_mid   - conv1 agg over sorted runs (4 thr/node, register acc),
//             fused 4->64->relu->4 matmul; writes z = t*dinv,
//             out = b2 + t*dinv^2.
//   k_acc2  - conv2 agg: out[c] += dinv[c] * sum z[r].

#define CSHIFT 10
#define CNODES 1024
#define KC_MAX 128
#define CAPC   18432     // coarse bucket capacity (mean 16327, ~+16 sigma)
#define EPB    4096      // edges per partition block
#define PTH    512
#define CURPAD 16
#define HCAP   9216      // half-bucket capacity (mean 8163, ~+11 sigma)
#define ANODES 128       // nodes per aggregation block
#define ACAP   2432      // agg staging capacity (mean 2041, ~+8 sigma)

__global__ void k_zero(int* __restrict__ p, int n) {
    int i = blockIdx.x * blockDim.x + threadIdx.x;
    if (i < n) p[i] = 0;
}

__global__ void __launch_bounds__(PTH) k_part(
        const int* __restrict__ row, const int* __restrict__ col,
        int e, int Kc, int* __restrict__ cursor, unsigned* __restrict__ ere) {
    __shared__ int wh[8][KC_MAX];    // per-wave hist -> per-wave cursors
    __shared__ int h[KC_MAX];
    __shared__ int loff[KC_MAX];
    __shared__ int gbase[KC_MAX];
    __shared__ unsigned staged[EPB];
    int t = threadIdx.x, w = t >> 6;
    for (int k = t; k < 8 * KC_MAX; k += PTH) ((int*)wh)[k] = 0;
    __syncthreads();
    int lo = blockIdx.x * EPB;
    int cbuf[8], rbuf[8];
#pragma unroll
    for (int k = 0; k < 8; ++k) {
        int i = lo + t + k * PTH;
        if (i < e) { cbuf[k] = col[i]; rbuf[k] = row[i]; }
        else { cbuf[k] = -1; rbuf[k] = 0; }
    }
#pragma unroll
    for (int k = 0; k < 8; ++k)
        if (cbuf[k] >= 0) atomicAdd(&wh[w][cbuf[k] >> CSHIFT], 1);
    __syncthreads();
    if (t < KC_MAX) {
        int s = 0;
#pragma unroll
        for (int w2 = 0; w2 < 8; ++w2) s += wh[w2][t];
        h[t] = s;
        loff[t] = s;
    }
    __syncthreads();
    for (int off = 1; off < KC_MAX; off <<= 1) {
        int v = (t < KC_MAX && t >= off) ? loff[t - off] : 0;
        __syncthreads();
        if (t < KC_MAX) loff[t] += v;
        __syncthreads();
    }
    if (t < KC_MAX) {
        int st = loff[t] - h[t];
        loff[t] = st;
        if (t < Kc && h[t]) gbase[t] = atomicAdd(&cursor[t * CURPAD], h[t]);
        int run = st;
#pragma unroll
        for (int w2 = 0; w2 < 8; ++w2) { int c = wh[w2][t]; wh[w2][t] = run; run += c; }
    }
    __syncthreads();
#pragma unroll
    for (int k = 0; k < 8; ++k) {
        int c = cbuf[k];
        if (c < 0) continue;
        int pos = atomicAdd(&wh[w][c >> CSHIFT], 1);
        staged[pos] = ((unsigned)rbuf[k] << CSHIFT) | (unsigned)(c & (CNODES - 1));
    }
    __syncthreads();
    int lane = t & 63;
    for (int k = w; k < Kc; k += 8) {
        int len = h[k];
        if (!len) continue;
        int gb = gbase[k], lb = loff[k];
        size_t dst = (size_t)k * CAPC + gb;
        for (int j = lane; j < len; j += 64)
            if (gb + j < CAPC) ere[dst + j] = staged[lb + j];
    }
}

// two blocks per bucket; records in VGPRs (rb[5]: 5*4*1024 = 20480 >= CAPC);
// single global read of the bucket.
__global__ void __launch_bounds__(1024) k_sortH(
        const int* __restrict__ cursor, unsigned* __restrict__ ere,
        int* __restrict__ rstart, const float4* __restrict__ x,
        float* __restrict__ dinv, float4* __restrict__ y, int n) {
    __shared__ int hist[CNODES];
    __shared__ int scn[CNODES];
    __shared__ int cur[CNODES];
    __shared__ unsigned sorted[HCAP];
    int bh = blockIdx.x, b = bh >> 1, h = bh & 1;
    int t = threadIdx.x, nlo = b << CSHIFT;
    hist[t] = 0;
    __syncthreads();
    size_t c0 = (size_t)b * CAPC;
    int m = min(cursor[b * CURPAD], CAPC);
    int n4 = m >> 2;                 // <= 4608
    const uint4* e4 = (const uint4*)(ere + c0);
    uint4 rb[5];
    int gv[5];
#pragma unroll
    for (int k = 0; k < 5; ++k) {
        int g = t + k * 1024;
        gv[k] = (g < n4);
        if (gv[k]) rb[k] = e4[g];
    }
    unsigned tailrec = 0xFFFFFFFFu;
    {
        int ti = (n4 << 2) + t;
        if (ti < m) tailrec = ere[c0 + ti];
    }
#pragma unroll
    for (int k = 0; k < 5; ++k) {
        if (!gv[k]) continue;
        atomicAdd(&hist[rb[k].x & (CNODES - 1)], 1);
        atomicAdd(&hist[rb[k].y & (CNODES - 1)], 1);
        atomicAdd(&hist[rb[k].z & (CNODES - 1)], 1);
        atomicAdd(&hist[rb[k].w & (CNODES - 1)], 1);
    }
    if (tailrec != 0xFFFFFFFFu) atomicAdd(&hist[tailrec & (CNODES - 1)], 1);
    __syncthreads();
    int hv = hist[t];
    scn[t] = hv;
    __syncthreads();
    for (int off = 1; off < CNODES; off <<= 1) {
        int v = (t >= off) ? scn[t - off] : 0;
        __syncthreads();
        scn[t] += v;
        __syncthreads();
    }
    int st = scn[t] - hv;            // exclusive start within bucket
    int low = scn[CNODES / 2 - 1];   // lower-half total
    rstart[(b << CSHIFT) + t] = (int)c0 + st;
    int base = h ? low : 0;
    cur[t] = st - base;              // placement cursor (valid for own half)
    if ((t >> 9) == h) {
        int node = nlo + t;
        if (node < n) {
            float di = rsqrtf((float)hv + 1.0f);
            dinv[node] = di;
            float4 xv = x[node];
            y[node] = make_float4(xv.x * di, xv.y * di, xv.z * di, xv.w * di);
        }
    }
    __syncthreads();
#pragma unroll
    for (int k = 0; k < 5; ++k) {
        if (!gv[k]) continue;
        unsigned e0 = rb[k].x, e1 = rb[k].y, e2 = rb[k].z, e3 = rb[k].w;
        int l0 = e0 & (CNODES - 1);
        if ((l0 >> 9) == h) { int p = atomicAdd(&cur[l0], 1); if (p < HCAP) sorted[p] = e0 >> CSHIFT; }
        int l1 = e1 & (CNODES - 1);
        if ((l1 >> 9) == h) { int p = atomicAdd(&cur[l1], 1); if (p < HCAP) sorted[p] = e1 >> CSHIFT; }
        int l2 = e2 & (CNODES - 1);
        if ((l2 >> 9) == h) { int p = atomicAdd(&cur[l2], 1); if (p < HCAP) sorted[p] = e2 >> CSHIFT; }
        int l3 = e3 & (CNODES - 1);
        if ((l3 >> 9) == h) { int p = atomicAdd(&cur[l3], 1); if (p < HCAP) sorted[p] = e3 >> CSHIFT; }
    }
    if (tailrec != 0xFFFFFFFFu) {
        int l = tailrec & (CNODES - 1);
        if ((l >> 9) == h) { int p = atomicAdd(&cur[l], 1); if (p < HCAP) sorted[p] = tailrec >> CSHIFT; }
    }
    __syncthreads();
    int cnt = h ? (m - low) : low;
    int wb = min(cnt, HCAP);
    for (int i = t; i < wb; i += 1024) ere[c0 + base + i] = sorted[i];
}

// conv1 aggregation (4 threads/node) + fused node matmul
__global__ void __launch_bounds__(512) k_mid(
        const unsigned* __restrict__ ere, const int* __restrict__ rstart,
        const int* __restrict__ cursor, const float* __restrict__ dinv,
        const float4* __restrict__ x, const float4* __restrict__ y,
        const float* __restrict__ W1, const float* __restrict__ b1,
        const float* __restrict__ W2, const float* __restrict__ b2,
        float4* __restrict__ z, float4* __restrict__ out, int n) {
    __shared__ unsigned recs[ACAP];
    __shared__ float4 sums[ANODES];
    int g = blockIdx.x, t = threadIdx.x;
    int nlo = g * ANODES;
    int b = nlo >> CSHIFT;
    int c0i = (int)((size_t)b * CAPC);
    int s0 = rstart[nlo];
    int e0 = ((g & 7) == 7) ? c0i + min(cursor[b * CURPAD], CAPC)
                            : rstart[nlo + ANODES];
    int len = min(e0 - s0, ACAP);
    for (int i = t; i < len; i += 512) recs[i] = ere[s0 + i];
    __syncthreads();
    int tt = t >> 2, q = t & 3;
    int s = rstart[nlo + tt] - s0;
    int epos = (tt == ANODES - 1) ? len : min(rstart[nlo + tt + 1] - s0, len);
    float vx = 0.f, vy = 0.f, vz = 0.f, vw = 0.f;
    int i = s + q;
    while (i + 12 < epos) {
        int r0 = recs[i], r1 = recs[i + 4], r2 = recs[i + 8], r3 = recs[i + 12];
        float4 a0 = y[r0], a1 = y[r1], a2 = y[r2], a3 = y[r3];
        vx += a0.x + a1.x + a2.x + a3.x;
        vy += a0.y + a1.y + a2.y + a3.y;
        vz += a0.z + a1.z + a2.z + a3.z;
        vw += a0.w + a1.w + a2.w + a3.w;
        i += 16;
    }
    for (; i < epos; i += 4) {
        float4 a = y[recs[i]];
        vx += a.x; vy += a.y; vz += a.z; vw += a.w;
    }
    vx += __shfl_xor(vx, 1); vx += __shfl_xor(vx, 2);
    vy += __shfl_xor(vy, 1); vy += __shfl_xor(vy, 2);
    vz += __shfl_xor(vz, 1); vz += __shfl_xor(vz, 2);
    vw += __shfl_xor(vw, 1); vw += __shfl_xor(vw, 2);
    if (q == 0) sums[tt] = make_float4(vx, vy, vz, vw);
    __syncthreads();
    int node = nlo + t;
    if (t < ANODES && node < n) {
        float di = dinv[node], sl = di * di;
        float4 sv = sums[t];
        float4 xv = x[node];
        float a0 = di * sv.x + xv.x * sl;
        float a1 = di * sv.y + xv.y * sl;
        float a2 = di * sv.z + xv.z * sl;
        float a3 = di * sv.w + xv.w * sl;
        float t0 = 0.f, t1 = 0.f, t2 = 0.f, t3 = 0.f;
#pragma unroll 8
        for (int j = 0; j < 64; ++j) {
            float hh = b1[j] + a0 * W1[j] + a1 * W1[64 + j] + a2 * W1[128 + j] + a3 * W1[192 + j];
            hh = fmaxf(hh, 0.f);
            t0 += hh * W2[j * 4 + 0];
            t1 += hh * W2[j * 4 + 1];
            t2 += hh * W2[j * 4 + 2];
            t3 += hh * W2[j * 4 + 3];
        }
        z[node] = make_float4(t0 * di, t1 * di, t2 * di, t3 * di);
        out[node] = make_float4(b2[0] + t0 * sl, b2[1] + t1 * sl,
                                b2[2] + t2 * sl, b2[3] + t3 * sl);
    }
}

__global__ void __launch_bounds__(512) k_acc2(
        const unsigned* __restrict__ ere, const int* __restrict__ rstart,
        const int* __restrict__ cursor, const float* __restrict__ dinv,
        const float4* __restrict__ z, float4* __restrict__ out, int n) {
    __shared__ unsigned recs[ACAP];
    __shared__ float4 sums[ANODES];
    int g = blockIdx.x, t = threadIdx.x;
    int nlo = g * ANODES;
    int b = nlo >> CSHIFT;
    int c0i = (int)((size_t)b * CAPC);
    int s0 = rstart[nlo];
    int e0 = ((g & 7) == 7) ? c0i + min(cursor[b * CURPAD], CAPC)
                            : rstart[nlo + ANODES];
    int len = min(e0 - s0, ACAP);
    for (int i = t; i < len; i += 512) recs[i] = ere[s0 + i];
    __syncthreads();
    int tt = t >> 2, q = t & 3;
    int s = rstart[nlo + tt] - s0;
    int epos = (tt == ANODES - 1) ? len : min(rstart[nlo + tt + 1] - s0, len);
    float vx = 0.f, vy = 0.f, vz = 0.f, vw = 0.f;
    int i = s + q;
    while (i + 12 < epos) {
        int r0 = recs[i], r1 = recs[i + 4], r2 = recs[i + 8], r3 = recs[i + 12];
        float4 a0 = z[r0], a1 = z[r1], a2 = z[r2], a3 = z[r3];
        vx += a0.x + a1.x + a2.x + a3.x;
        vy += a0.y + a1.y + a2.y + a3.y;
        vz += a0.z + a1.z + a2.z + a3.z;
        vw += a0.w + a1.w + a2.w + a3.w;
        i += 16;
    }
    for (; i < epos; i += 4) {
        float4 a = z[recs[i]];
        vx += a.x; vy += a.y; vz += a.z; vw += a.w;
    }
    vx += __shfl_xor(vx, 1); vx += __shfl_xor(vx, 2);
    vy += __shfl_xor(vy, 1); vy += __shfl_xor(vy, 2);
    vz += __shfl_xor(vz, 1); vz += __shfl_xor(vz, 2);
    vw += __shfl_xor(vw, 1); vw += __shfl_xor(vw, 2);
    if (q == 0) sums[tt] = make_float4(vx, vy, vz, vw);
    __syncthreads();
    int node = nlo + t;
    if (t < ANODES && node < n) {
        float di = dinv[node];
        float4 sv = sums[t];
        float4 o = out[node];
        out[node] = make_float4(o.x + di * sv.x, o.y + di * sv.y,
                                o.z + di * sv.z, o.w + di * sv.w);
    }
}

extern "C" void kernel_launch(void* const* d_in, const int* in_sizes, int n_in,
                              void* d_out, int out_size, void* d_ws, size_t ws_size,
                              hipStream_t stream) {
    const float* x  = (const float*)d_in[0];
    const int* edge = (const int*)d_in[1];
    const float* W1 = (const float*)d_in[2];
    const float* b1 = (const float*)d_in[3];
    const float* W2 = (const float*)d_in[4];
    const float* b2 = (const float*)d_in[5];
    float* out = (float*)d_out;

    const int n = in_sizes[0] / 4;   // N nodes (S=4)
    const int e = in_sizes[1] / 2;   // E edges
    const int* row = edge;
    const int* col = edge + e;
    const int Kc = (n + CNODES - 1) >> CSHIFT;   // 98 coarse buckets

    char* ws = (char*)d_ws;
    float* y    = (float*)ws;  ws += (size_t)4 * n * 4;
    float* zmid = (float*)ws;  ws += (size_t)4 * n * 4;
    float* dinv = (float*)ws;  ws += (size_t)n * 4;
    unsigned* ere = (unsigned*)ws;  ws += (size_t)Kc * CAPC * 4;
    int* cursor = (int*)ws;    ws += (size_t)Kc * CURPAD * 4;
    int* rstart = (int*)ws;    ws += (size_t)Kc * CNODES * 4;

    const int B = 256;
    const int gp = (e + EPB - 1) / EPB;          // 391
    const int ga = (n + ANODES - 1) / ANODES;    // 782
    const int nz = Kc * CURPAD;

    k_zero<<<(nz + B - 1) / B, B, 0, stream>>>(cursor, nz);
    k_part<<<gp, PTH, 0, stream>>>(row, col, e, Kc, cursor, ere);
    k_sortH<<<2 * Kc, 1024, 0, stream>>>(cursor, ere, rstart, (const float4*)x,
                                         dinv, (float4*)y, n);
    k_mid<<<ga, 512, 0, stream>>>(ere, rstart, cursor, dinv, (const float4*)x,
                                  (const float4*)y, W1, b1, W2, b2,
                                  (float4*)zmid, (float4*)out, n);
    k_acc2<<<ga, 512, 0, stream>>>(ere, rstart, cursor, dinv,
                                   (const float4*)zmid, (float4*)out, n);
}